// Round 1
// 410.968 us; speedup vs baseline: 1.0408x; 1.0408x over previous
//
#include <hip/hip_runtime.h>
#include <math.h>

// HyperbolicParamAdapter: expmap0 -> mobius diag scale -> project -> logmap0
// out_i = p_i * w_i * total, total = s1*s2*pf*s3 where the scalar chain
// depends only on two row reductions: sum(p_i^2) and sum((p_i*w_i)^2).
// One wave (64 lanes) per row of 512 floats: 2x float4 per lane, butterfly
// shuffle reduction, redundant per-lane scalar math, one coalesced write.
//
// R2: replaced libm tanhf/atanhf/sqrtf (branchy software routines, ~100+
// VALU instrs each) with raw HW transcendentals (v_exp_f32/v_log_f32/
// v_rcp_f32/v_sqrt_f32, ~1 ulp). All args are nonneg + bounded:
//   tanh(x>=0)      = (1-t)/(1+t), t = exp2(-2x*log2e)
//   artanh(z in[0,1)) = 0.5*ln2*(log2(1+z)-log2(1-z))
// Also nontemporal hints on the 537 MB streamed read/write.
// Timed graph = 2 poison fills (~325 us, fixed) + this kernel (~103 us -> target ~86 us).

#define SQRT_C    0.1f
#define MIN_NORM  1e-5f
#define CLAMP_EPS 1e-5f
#define LOG2E     1.4426950408889634f
#define HALF_LN2  0.34657359027997264f

typedef float f32x4 __attribute__((ext_vector_type(4)));

__device__ __forceinline__ float fexp2(float x){ float r; asm("v_exp_f32 %0, %1" : "=v"(r) : "v"(x)); return r; }
__device__ __forceinline__ float flog2(float x){ float r; asm("v_log_f32 %0, %1" : "=v"(r) : "v"(x)); return r; }
__device__ __forceinline__ float frcp (float x){ float r; asm("v_rcp_f32 %0, %1" : "=v"(r) : "v"(x)); return r; }
__device__ __forceinline__ float fsqrt_(float x){ float r; asm("v_sqrt_f32 %0, %1" : "=v"(r) : "v"(x)); return r; }

// tanh for x >= 0 (no overflow: t -> 0 for large x, tanh -> 1)
__device__ __forceinline__ float tanh_pos(float x){
    float t = fexp2(-2.0f * LOG2E * x);
    return (1.0f - t) * frcp(1.0f + t);
}
// artanh for z in [0, 1): 1-z is exact (Sterbenz) for z in [0.5,1), so the
// sensitive log2(1-z) term near the z~0.978 operating point stays ~1 ulp.
__device__ __forceinline__ float atanh01(float z){
    return HALF_LN2 * (flog2(1.0f + z) - flog2(1.0f - z));
}

__global__ __launch_bounds__(256) void hyper_adapter_kernel(
    const float* __restrict__ params,
    const float* __restrict__ weights,
    float* __restrict__ out,
    int n_rows)
{
    const int lane = threadIdx.x & 63;
    const int wave = threadIdx.x >> 6;                 // 0..3 waves per block
    const int row  = blockIdx.x * 4 + wave;
    if (row >= n_rows) return;

    const f32x4* prow = (const f32x4*)(params + (size_t)row * 512);
    const f32x4* wv   = (const f32x4*)weights;
    f32x4*       orow = (f32x4*)(out + (size_t)row * 512);

    // lane i holds row elements [4i..4i+3] and [256+4i..256+4i+3] (coalesced)
    f32x4 p0 = __builtin_nontemporal_load(&prow[lane]);
    f32x4 p1 = __builtin_nontemporal_load(&prow[64 + lane]);
    f32x4 w0 = wv[lane];          // weights stay cached (reused by all rows)
    f32x4 w1 = wv[64 + lane];

    f32x4 m0 = p0 * w0;
    f32x4 m1 = p1 * w1;

    float sp  = p0.x * p0.x + p0.y * p0.y + p0.z * p0.z + p0.w * p0.w
              + p1.x * p1.x + p1.y * p1.y + p1.z * p1.z + p1.w * p1.w;
    float spw = m0.x * m0.x + m0.y * m0.y + m0.z * m0.z + m0.w * m0.w
              + m1.x * m1.x + m1.y * m1.y + m1.z * m1.z + m1.w * m1.w;

    // 64-lane butterfly reduction (all lanes end with the full sums)
    #pragma unroll
    for (int off = 32; off > 0; off >>= 1) {
        sp  += __shfl_xor(sp,  off, 64);
        spw += __shfl_xor(spw, off, 64);
    }

    // ---- scalar chain (redundant across lanes, ~35 VALU ops) ----
    float pn     = fsqrt_(sp);                      // ||p|| (unclamped)
    float u_norm = fmaxf(pn, MIN_NORM);             // _norm(params)
    float a      = SQRT_C * u_norm;
    float s1     = tanh_pos(a) * frcp(a);           // x = s1 * p

    float x_norm  = fmaxf(s1 * pn, MIN_NORM);       // _norm(x) = max(||x||, 1e-5)
    float mx_norm = s1 * fsqrt_(spw);               // ||mx|| (NOT clamped, per ref)

    float z1 = fminf(SQRT_C * x_norm, 1.0f - CLAMP_EPS);   // z1 >= 0 always
    float th = tanh_pos(mx_norm * frcp(x_norm) * atanh01(z1));
    float s2 = th * frcp(mx_norm * SQRT_C);         // res = s2 * mx = s2 * s1 * (p.w)

    float res_norm = th * 10.0f;                    // ||res|| = th/sqrt(c), th >= 0
    // _project
    float rn      = fmaxf(res_norm, MIN_NORM);
    const float maxnorm = (1.0f - 0.001f) / SQRT_C; // 9.99
    float pf      = (rn > maxnorm) ? (maxnorm * frcp(rn)) : 1.0f;

    // logmap0
    float y_norm = fmaxf(res_norm * pf, MIN_NORM);
    float z2 = fminf(SQRT_C * y_norm, 1.0f - CLAMP_EPS);
    float s3 = atanh01(z2) * frcp(y_norm * SQRT_C);

    float total = s1 * s2 * pf * s3;                // applied to m (= p*w)

    __builtin_nontemporal_store(m0 * total, &orow[lane]);
    __builtin_nontemporal_store(m1 * total, &orow[64 + lane]);
}

extern "C" void kernel_launch(void* const* d_in, const int* in_sizes, int n_in,
                              void* d_out, int out_size, void* d_ws, size_t ws_size,
                              hipStream_t stream) {
    const float* params  = (const float*)d_in[0];
    const float* weights = (const float*)d_in[1];
    float* out = (float*)d_out;

    const int n_rows = in_sizes[0] / 512;           // 131072 rows of d=512
    const int blocks = (n_rows + 3) / 4;            // 4 rows (waves) per block

    hyper_adapter_kernel<<<blocks, 256, 0, stream>>>(params, weights, out, n_rows);
}